// Round 14
// baseline (421.003 us; speedup 1.0000x reference)
//
#include <hip/hip_runtime.h>
#include <cstdint>
#include <cstddef>

// ---------------- problem dims ----------------
#define NB 4096   // batch
#define NE 768    // in features
#define NH 2048   // hidden
#define NKF 128   // GP feature dim
#define NC 200    // classes
#define NN 20     // inducing points per class
#define NITER_R 6   // iterations on G^4 (== 24 on G)

typedef __attribute__((ext_vector_type(8))) short s16x8;
typedef __attribute__((ext_vector_type(8))) unsigned short u16x8;
typedef __attribute__((ext_vector_type(4))) unsigned short u16x4;
typedef __attribute__((ext_vector_type(4))) float f32x4;

__device__ inline unsigned short f2bf(float x) {
  unsigned u = __builtin_bit_cast(unsigned, x);
  u += 0x7fffu + ((u >> 16) & 1u);
  return (unsigned short)(u >> 16);
}
__device__ inline float bf2f(unsigned short h) {
  return __builtin_bit_cast(float, (unsigned)h << 16);
}
__device__ inline float gelu_exact(float x) {
  return x * 0.5f * (1.0f + erff(x * 0.70710678118654752f));
}

// async global->LDS 16B/lane. lds base must be wave-uniform; HW writes base+lane*16.
__device__ inline void gl16(const unsigned short* g, unsigned short* l) {
  __builtin_amdgcn_global_load_lds(
      (const __attribute__((address_space(1))) unsigned int*)(uintptr_t)(g),
      (__attribute__((address_space(3))) unsigned int*)(uintptr_t)(l),
      16, 0, 0);
}

// ---------------- workspace layout (bytes) ----------------
constexpr size_t SZ_W1BF = (size_t)NH * NE * 2;
constexpr size_t SZ_W2BF = (size_t)NH * NH * 2;
constexpr size_t SZ_WPBF = (size_t)NKF * NH * 2;
constexpr size_t SZ_SLOT = (size_t)NB * NH * 2;  // 16.8 MB

constexpr size_t OFF_W1BF = 0;                    // persistent unscaled bf16 weights
constexpr size_t OFF_W2BF = OFF_W1BF + SZ_W1BF;
constexpr size_t OFF_WPBF = OFF_W2BF + SZ_W2BF;
constexpr size_t OFF_XBF  = OFF_WPBF + SZ_WPBF;  // slot A
constexpr size_t OFF_H2BF = OFF_XBF;             // gemm2 out (slot A reuse)
constexpr size_t OFF_H1BF = OFF_XBF + SZ_SLOT;   // slot B
constexpr size_t OFF_H1N  = OFF_H1BF + SZ_SLOT;  // slot C
constexpr size_t OFF_HP   = OFF_H1N + SZ_SLOT;   // zpad region (2MB)
constexpr size_t OFF_H2S  = OFF_HP + (size_t)NB * NKF * 4;  // |h|^2 per row
constexpr size_t OFF_PV   = OFF_H2S + (size_t)NB * 4;       // iter vectors + norm slots
constexpr size_t OFF_SINV = OFF_PV + (size_t)3 * 3 * 2048 * 4;
constexpr size_t OFF_Z2   = OFF_SINV + 256;
constexpr size_t OFF_LC   = OFF_Z2 + (size_t)NC * NN * 4;
constexpr size_t OFF_AL   = OFF_LC + (size_t)NC * NN * NN * 4;
constexpr size_t WS_NEED  = OFF_AL + (size_t)NC * NN * 4;

// zpad: bf16 [200][32][128] = 1.64 MB, lives in the OFF_HP region (2 MB)
constexpr size_t OFF_ZPD = OFF_HP;
static_assert((size_t)NC * 32 * NKF * 2 <= (size_t)NB * NKF * 4, "zpad overflow");

// --- slot A sublayout (gram phase + Xbf; all dead before H2bf overwrites) ---
constexpr size_t GOFF_W1T   = OFF_XBF;                            // bf16 [768][2048]
constexpr size_t GOFF_GPACC = GOFF_W1T + (size_t)NE * NH * 2;     // f32 128^2
constexpr size_t GOFF_G1SA  = GOFF_GPACC + (size_t)NKF * NKF * 4; // bf16 768^2 (G, then G^4)
constexpr size_t GOFF_G1SB  = GOFF_G1SA + (size_t)NE * NE * 2;    // bf16 768^2 (G^2)
constexpr size_t OFF_XBF2   = GOFF_G1SB + (size_t)NE * NE * 2;    // bf16 [4096][768] ln1 out
static_assert(OFF_XBF2 + (size_t)NB * NE * 2 <= OFF_XBF + SZ_SLOT, "slotA overflow");
// slot B: G2sA / G2sB bf16 2048^2 each (ping-pong: G -> G^2 -> G^4 back to A)
constexpr size_t GOFF_G2SA = OFF_H1BF;
constexpr size_t GOFF_G2SB = OFF_H1BF + (size_t)NH * NH * 2;
// --- GP-phase aliases ---
constexpr size_t OFF_HPBF  = OFF_H1BF;                         // bf16 [4096][128] (slot B)
constexpr size_t OFF_PPROJ = OFF_H1N;                          // bf16 [8][4096][128] (slot C)
constexpr size_t OFF_LGT   = OFF_H1N;                          // f32 [200][4096] logitsT
constexpr size_t OFF_VART  = OFF_LGT + (size_t)NC * NB * 4;    // f32 [200][4096] var_c
static_assert(OFF_VART + (size_t)NC * NB * 4 <= OFF_H1N + SZ_SLOT, "slotC overflow");

// ==================== prep_bulk: register-homogeneous memory work only ====================
__global__ __launch_bounds__(256) void prep_bulk(const float* __restrict__ X,
                                                 const float* __restrict__ g1,
                                                 const float* __restrict__ be1,
                                                 const float* __restrict__ W1,
                                                 const float* __restrict__ W2,
                                                 const float* __restrict__ Wp,
                                                 unsigned short* __restrict__ W1T,
                                                 unsigned short* __restrict__ W1bf,
                                                 unsigned short* __restrict__ W2bf,
                                                 unsigned short* __restrict__ Wpbf,
                                                 unsigned short* __restrict__ Xbf,
                                                 float* __restrict__ Gpacc,
                                                 float* __restrict__ slots) {
  int b = blockIdx.x, t = threadIdx.x;
  if (b < 384) {
    __shared__ float tile[64][65];
    int bx = b % 12, by = b / 12;
    int c0 = bx * 64, r0 = by * 64;
    int tx = t & 63, ty = t >> 6;
    #pragma unroll
    for (int j = 0; j < 16; ++j) {
      int r = ty + j * 4;
      float v = W1[(size_t)(r0 + r) * NE + c0 + tx];
      tile[r][tx] = v;
      W1bf[(size_t)(r0 + r) * NE + c0 + tx] = f2bf(v);
    }
    __syncthreads();
    #pragma unroll
    for (int j = 0; j < 16; ++j) {
      int cc = ty + j * 4;
      W1T[(size_t)(c0 + cc) * NH + r0 + tx] = f2bf(tile[tx][cc]);
    }
  } else if (b < 896) {
    const int n2v = (NH * NH) / 4;
    const int npv = (NKF * NH) / 4;
    int idx = (b - 384) * 256 + t;
    const int stride = 512 * 256;
    for (int i = idx; i < n2v + npv; i += stride) {
      const float* src; unsigned short* dst; int off;
      if (i < n2v) { src = W2; dst = W2bf; off = i; }
      else         { src = Wp; dst = Wpbf; off = i - n2v; }
      float4 v = *(const float4*)(src + (size_t)off * 4);
      u16x4 o;
      o[0] = f2bf(v.x); o[1] = f2bf(v.y); o[2] = f2bf(v.z); o[3] = f2bf(v.w);
      *(u16x4*)(dst + (size_t)off * 4) = o;
    }
  } else if (b < 1920) {
    int wid = t >> 6, lane = t & 63;
    int row = (b - 896) * 4 + wid;
    const float* xr = X + (size_t)row * NE;
    float4 v[3];
    float s = 0.f, sq = 0.f;
    #pragma unroll
    for (int j = 0; j < 3; ++j) {
      v[j] = *(const float4*)(xr + j * 256 + lane * 4);
      s += v[j].x + v[j].y + v[j].z + v[j].w;
      sq += v[j].x * v[j].x + v[j].y * v[j].y + v[j].z * v[j].z + v[j].w * v[j].w;
    }
    for (int off = 32; off; off >>= 1) { s += __shfl_down(s, off); sq += __shfl_down(sq, off); }
    s = __shfl(s, 0); sq = __shfl(sq, 0);
    float mean = s * (1.0f / NE);
    float var = sq * (1.0f / NE) - mean * mean;
    float rstd = rsqrtf(var + 1e-5f);
    unsigned short* orow = Xbf + (size_t)row * NE;
    #pragma unroll
    for (int j = 0; j < 3; ++j) {
      int e0 = j * 256 + lane * 4;
      float4 gg = *(const float4*)(g1 + e0);
      float4 bb = *(const float4*)(be1 + e0);
      u16x4 o;
      o[0] = f2bf((v[j].x - mean) * rstd * gg.x + bb.x);
      o[1] = f2bf((v[j].y - mean) * rstd * gg.y + bb.y);
      o[2] = f2bf((v[j].z - mean) * rstd * gg.z + bb.z);
      o[3] = f2bf((v[j].w - mean) * rstd * gg.w + bb.w);
      *(u16x4*)(orow + e0) = o;
    }
  } else if (b < 1924) {
    float4 z = {0.f, 0.f, 0.f, 0.f};
    int base = (b - 1920) * 1024 + t;
    #pragma unroll
    for (int q = 0; q < 4; ++q) *((float4*)Gpacc + base + q * 256) = z;
  } else {
    if (t < 32) slots[t] = 0.f;
  }
}

// ==================== gp_prep: z2, Cholesky, alpha, L^-1, zpad (bf16 padded Z) ====================
__global__ __launch_bounds__(128) void gp_prep(const float* __restrict__ z,
                                               const float* __restrict__ vm,
                                               const float* __restrict__ ll,
                                               float* __restrict__ z2g,
                                               float* __restrict__ Lig,
                                               float* __restrict__ alphag,
                                               unsigned short* __restrict__ zpad) {
  int c = blockIdx.x, t = threadIdx.x;
  __shared__ float zc[NN * NKF];
  __shared__ float Amat[NN][NN + 1];
  __shared__ float Li[NN][NN + 1];
  __shared__ float z2s[NN], ys[NN], al[NN];
  const float* zcg = z + (size_t)c * NN * NKF;
  for (int i = t; i < NN * NKF; i += 128) zc[i] = zcg[i];
  __syncthreads();
  if (t < NN) {
    float s = 0.f;
    for (int k = 0; k < NKF; ++k) { float v = zc[t * NKF + k]; s += v * v; }
    z2s[t] = s;
    z2g[c * NN + t] = s;
  }
  __syncthreads();
  float inv2 = 0.5f * expf(-2.0f * ll[0]);
  for (int e = t; e < NN * NN; e += 128) {
    int n = e / NN, m = e % NN;
    float d = 0.f;
    for (int k = 0; k < NKF; ++k) d += zc[n * NKF + k] * zc[m * NKF + k];
    float d2 = fmaxf(z2s[n] + z2s[m] - 2.0f * d, 0.0f);
    float v = expf(-d2 * inv2);
    if (n == m) v += 1e-4f;
    Amat[n][m] = v;
  }
  __syncthreads();
  for (int j = 0; j < NN; ++j) {
    if (t == 0) {
      float s = Amat[j][j];
      for (int p = 0; p < j; ++p) s -= Amat[j][p] * Amat[j][p];
      Amat[j][j] = sqrtf(s);
    }
    __syncthreads();
    if (t > j && t < NN) {
      float s = Amat[t][j];
      for (int p = 0; p < j; ++p) s -= Amat[t][p] * Amat[j][p];
      Amat[t][j] = s / Amat[j][j];
    }
    __syncthreads();
  }
  if (t < NN) {
    int j = t;
    for (int n = 0; n < NN; ++n) {
      float s;
      if (n < j) s = 0.f;
      else {
        s = (n == j) ? 1.f : 0.f;
        for (int m = j; m < n; ++m) s -= Amat[n][m] * Li[m][j];
        s /= Amat[n][n];
      }
      Li[n][j] = s;
    }
  }
  if (t == 0) {
    const float* mc = vm + c * NN;
    for (int n = 0; n < NN; ++n) {
      float s = mc[n];
      for (int m = 0; m < n; ++m) s -= Amat[n][m] * ys[m];
      ys[n] = s / Amat[n][n];
    }
    for (int n = NN - 1; n >= 0; --n) {
      float s = ys[n];
      for (int m = n + 1; m < NN; ++m) s -= Amat[m][n] * al[m];
      al[n] = s / Amat[n][n];
    }
  }
  __syncthreads();
  for (int e = t; e < NN * NN; e += 128)
    Lig[(size_t)c * NN * NN + e] = Li[e / NN][e % NN];
  if (t < NN) alphag[c * NN + t] = al[t];
  unsigned short* zp = zpad + (size_t)c * 32 * NKF;
  for (int i = t; i < 32 * NKF; i += 128) {
    int n = i >> 7;
    zp[i] = (n < NN) ? f2bf(zc[n * NKF + (i & 127)]) : (unsigned short)0;
  }
}

// ==================== symmetric dual-job gram GEMM (unsplit K) + folded Gp jobs ====================
// [0,21): G1 (tri 6x6 tiles, full K); [21,157): G2 (tri 16x16, full K).
// extra==1: blocks [157,173) = Gp = Wp*Wp^T split-K16, fp32 atomics into Gpacc.
// extra==2: block 157 = gp_power on Gpacc -> sinv[2] (reuses As/Bs LDS).
__global__ __launch_bounds__(256) void gemm_multi(const unsigned short* __restrict__ A1, int K1,
                                                  unsigned short* __restrict__ O1,
                                                  const unsigned short* __restrict__ A2, int K2,
                                                  unsigned short* __restrict__ O2,
                                                  const unsigned short* __restrict__ Wpb,
                                                  float* __restrict__ Gpacc,
                                                  float* __restrict__ sinv,
                                                  float cscale, int extra) {
  __shared__ __align__(16) unsigned short As[2][128 * 32];
  __shared__ __align__(16) unsigned short Bs[2][128 * 32];
  __shared__ __align__(16) unsigned short Tb[64][136];
  int b = blockIdx.x, t = threadIdx.x;

  if (extra == 2 && b == 157) {
    float* vv = (float*)&As[0][0];
    float* nacc = vv + 160;
    float (*pred)[NKF] = (float(*)[NKF]) & Bs[0][0];
    int rg = (t & 31) * 4;
    int ks2 = t >> 5;
    f32x4 Greg[16];
    #pragma unroll
    for (int kk = 0; kk < 16; ++kk)
      Greg[kk] = *(const f32x4*)(Gpacc + (size_t)(ks2 * 16 + kk) * NKF + rg);
    if (t < NKF) vv[t] = 1.0f;
    __syncthreads();
    float s_last0 = 1.f, s_last1 = 1.f;
    for (int it = 0; it < 40; ++it) {
      f32x4 p = {0.f, 0.f, 0.f, 0.f};
      #pragma unroll
      for (int kq = 0; kq < 4; ++kq) {
        f32x4 vq = *(const f32x4*)&vv[ks2 * 16 + kq * 4];
        p += Greg[kq * 4 + 0] * vq[0];
        p += Greg[kq * 4 + 1] * vq[1];
        p += Greg[kq * 4 + 2] * vq[2];
        p += Greg[kq * 4 + 3] * vq[3];
      }
      *(f32x4*)&pred[ks2][rg] = p;
      __syncthreads();
      float s = 0.f;
      if (t < NKF) {
        #pragma unroll
        for (int q = 0; q < 8; ++q) s += pred[q][t];
        vv[t] = s;
      }
      if (it >= 38) {
        float q2 = (t < NKF) ? s * s : 0.f;
        #pragma unroll
        for (int off = 32; off; off >>= 1) q2 += __shfl_down(q2, off);
        if (t == 0) nacc[0] = q2;
        if (t == 64) nacc[1] = q2;
      }
      __syncthreads();
      if (it == 38 && t == 0) s_last0 = nacc[0] + nacc[1];
      if (it == 39 && t == 0) s_last1 = nacc[0] + nacc[1];
    }
    if (t == 0) sinv[2] = powf(s_last1 / s_last0, -0.25f);
    return;
  }

  int epimode = 0;
  const unsigned short* A;
  unsigned short* Cout = nullptr;
  int Kk, Nn, kb, ke, bm0, bn0;
  if (extra == 1 && b >= 157) {
    int idx = b - 157;
    A = Wpb; Kk = K2; Nn = NKF;
    kb = idx * 128; ke = kb + 128;
    bm0 = 0; bn0 = 0;
    epimode = 1;
  } else {
    int ti;
    if (b < 21) {
      ti = b;
      A = A1; Kk = K1; Nn = NE;
      Cout = O1;
    } else {
      ti = b - 21;
      A = A2; Kk = K2; Nn = NH;
      Cout = O2;
    }
    kb = 0; ke = Kk;
    int ri = 0;
    while ((ri + 1) * (ri + 2) / 2 <= ti) ++ri;
    int rj = ti - ri * (ri + 1) / 2;
    bm0 = ri * 128; bn0 = rj * 128;
  }

  int wid = t >> 6, lane = t & 63;
  int wm = wid >> 1, wn = wid & 1;
  f32x4 acc[4][4] = {};

  int lrow = t >> 2;
  int lk8 = (((t & 3) ^ ((t >> 3) & 3)) * 8);
  const unsigned short* Ag = A + (size_t)(bm0 + lrow) * Kk + lk8;
  const unsigned short* Bg = A + (size_t)(bn0 + lrow) * Kk + lk8;

  int arow = wm * 64 + (lane & 15);
  int brow = wn * 64 + (lane & 15);
  int kca = (((lane >> 4) ^ ((arow >> 1) & 3)) * 8);
  int kcb = (((lane >> 4) ^ ((brow >> 1) & 3)) * 8);

  #define STAGEM(nb, koff)                                  \
    do {                                                    \
      gl16(Ag + (koff), &As[nb][wid * 512]);                \
      gl16(Ag + (size_t)64 * Kk + (koff), &As[nb][2048 + wid * 512]); \
      gl16(Bg + (koff), &Bs[nb][wid * 512]);                \
      gl16(Bg + (size_t)64 * Kk + (koff), &Bs[nb][2048 + wid * 512]); \
    } while (0)

  STAGEM(0, kb);
  __syncthreads();
  int cb = 0;
  for (int ks = kb; ks < ke; ks += 32) {
    if (ks + 32 < ke) STAGEM(cb ^ 1, ks + 32);
    s16x8 af[4], bfr[4];
    #pragma unroll
    for (int i = 0; i < 4; ++i) af[i] = *(const s16x8*)&As[cb][(arow + i * 16) * 32 + kca];
    #pragma unroll
    for (int j = 0; j < 4; ++j) bfr[j] = *(const s16x8*)&Bs[cb][(brow + j * 16) * 32 + kcb];
    #pragma unroll
    for (int i = 0; i < 4; ++i)
      #pragma unroll
      for (int j = 0; j < 4; ++j)
        acc[i][j] = __builtin_amdgcn_mfma_f32_16x16x32_bf16(af[i], bfr[j], acc[i][j], 0, 0, 0);
    __syncthreads();
    cb ^= 1;
  }
  #undef STAGEM

  int crow0 = bm0 + wm * 64 + (lane >> 4) * 4;
  int ccol0 = bn0 + wn * 64 + (lane & 15);
  if (epimode == 1) {
    #pragma unroll
    for (int i = 0; i < 4; ++i)
      #pragma unroll
      for (int j = 0; j < 4; ++j) {
        int col = ccol0 + j * 16;
        #pragma unroll
        for (int r = 0; r < 4; ++r) {
          int row = crow0 + i * 16 + r;
          atomicAdd(&Gpacc[(size_t)row * NKF + col], acc[i][j][r]);
        }
      }
    return;
  }

  #pragma unroll
  for (int i = 0; i < 4; ++i)
    #pragma unroll
    for (int j = 0; j < 4; ++j) {
      int col = ccol0 + j * 16;
      #pragma unroll
      for (int r = 0; r < 4; ++r) {
        int row = crow0 + i * 16 + r;
        Cout[(size_t)row * Nn + col] = f2bf(acc[i][j][r] * cscale);
      }
    }

  if (bm0 != bn0) {
    #pragma unroll
    for (int h = 0; h < 2; ++h) {
      __syncthreads();
      if (wn == h) {
        #pragma unroll
        for (int i = 0; i < 4; ++i)
          #pragma unroll
          for (int j = 0; j < 4; ++j) {
            int lc = j * 16 + (lane & 15);
            #pragma unroll
            for (int r = 0; r < 4; ++r) {
              int lr = wm * 64 + i * 16 + (lane >> 4) * 4 + r;
              Tb[lc][lr] = f2bf(acc[i][j][r] * cscale);
            }
          }
      }
      __syncthreads();
      int c = t >> 2;
      int rs = (t & 3) * 32;
      unsigned short* dst = Cout + (size_t)(bn0 + h * 64 + c) * Nn + bm0 + rs;
      #pragma unroll
      for (int q = 0; q < 4; ++q) *(u16x8*)(dst + q * 8) = *(const u16x8*)&Tb[c][rs + q * 8];
    }
  }
}

// ==================== gram power iteration (reads G^4 directly) ====================
__global__ __launch_bounds__(256) void gram_iter(const unsigned short* __restrict__ G1s,
                                                 const unsigned short* __restrict__ G2s,
                                                 float* __restrict__ vb,
                                                 float* __restrict__ slots, int iter) {
  int b = blockIdx.x, t = threadIdx.x;
  int m, r0, Kd;
  const unsigned short* gs;
  if (b < 96) { m = 0; gs = G1s; Kd = NE; r0 = b * 8; }
  else        { m = 1; gs = G2s; Kd = NH; r0 = (b - 96) * 8; }

  const float* vin = vb + ((size_t)m * 2 + (iter & 1)) * 2048;
  float* vout      = vb + ((size_t)m * 2 + ((iter + 1) & 1)) * 2048;

  __shared__ float vs[2048];
  if (iter > 0) {
    for (int k = t; k < Kd; k += 256) vs[k] = vin[k];
    __syncthreads();
  }

  int w = t >> 6, lane = t & 63;
  float nrm = 0.f;
  #pragma unroll
  for (int rr = 0; rr < 2; ++rr) {
    int row = r0 + w * 2 + rr;
    const unsigned short* g0 = gs + (size_t)row * Kd;
    float s = 0.f;
    for (int k0 = lane * 8; k0 < Kd; k0 += 512) {
      u16x8 u = *(const u16x8*)(g0 + k0);
      #pragma unroll
      for (int q = 0; q < 8; ++q) s += (iter == 0) ? bf2f(u[q]) : bf2f(u[q]) * vs[k0 + q];
    }
    for (int off = 32; off; off >>= 1) s += __shfl_down(s, off);
    if (lane == 0) { vout[row] = s; nrm += s * s; }
  }
  if (lane == 0) atomicAdd(&slots[m * 16 + iter + 1], nrm);
}

// ==================== ln_h ====================
__global__ __launch_bounds__(256) void ln_h(const unsigned short* __restrict__ X,
                                            const float* __restrict__ g,
                                            const float* __restrict__ b,
                                            unsigned short* __restrict__ out) {
  int wid = threadIdx.x >> 6, lane = threadIdx.x & 63;
  int row = blockIdx.x * 4 + wid;
  const unsigned short* xr = X + (size_t)row * NH;
  float xv[32];
  float s = 0.f, sq = 0.f;
  #pragma unroll
  for (int j = 0; j < 4; ++j) {
    u16x8 u = *(const u16x8*)(xr + j * 512 + lane * 8);
    #pragma unroll
    for (int q = 0; q < 8; ++q) {
      float x = bf2f(u[q]);
      xv[j * 8 + q] = x; s += x; sq += x * x;
    }
  }
  for (int off = 32; off; off >>= 1) { s += __shfl_down(s, off); sq += __shfl_down(sq, off); }
  s = __shfl(s, 0); sq = __shfl(sq, 0);
  float mean = s * (1.0f / NH);
  float var = sq * (1.0f / NH) - mean * mean;
  float rstd = rsqrtf(var + 1e-5f);
  unsigned short* orow = out + (size_t)row * NH;
  #pragma unroll
  for (int j = 0; j < 4; ++j) {
    int e0 = j * 512 + lane * 8;
    float4 ga = *(const float4*)(g + e0);
    float4 gb = *(const float4*)(g + e0 + 4);
    float4 ba = *(const float4*)(b + e0);
    float4 bb = *(const float4*)(b + e0 + 4);
    u16x8 o;
    o[0] = f2bf((xv[j*8+0] - mean) * rstd * ga.x + ba.x);
    o[1] = f2bf((xv[j*8+1] - mean) * rstd * ga.y + ba.y);
    o[2] = f2bf((xv[j*8+2] - mean) * rstd * ga.z + ba.z);
    o[3] = f2bf((xv[j*8+3] - mean) * rstd * ga.w + ba.w);
    o[4] = f2bf((xv[j*8+4] - mean) * rstd * gb.x + bb.x);
    o[5] = f2bf((xv[j*8+5] - mean) * rstd * gb.y + bb.y);
    o[6] = f2bf((xv[j*8+6] - mean) * rstd * gb.z + bb.z);
    o[7] = f2bf((xv[j*8+7] - mean) * rstd * gb.w + bb.w);
    *(u16x8*)(orow + e0) = o;
  }
}

// ==================== bf16 MFMA GEMM (NT), 2-phase dbuf + T2 XOR swizzle ====================
// sigmode 1: sc = sigma^-1 derived inline from power-iter slots.
// EPI 0: gelu(acc*sc+bias)->bf16. EPI 2: raw bf16 partials per blockIdx.z (split-K).
template <int EPI>
__global__ __launch_bounds__(256) void gemm_nt(const unsigned short* __restrict__ A,
                                               const unsigned short* __restrict__ Bm,
                                               const float* __restrict__ bias,
                                               void* __restrict__ Cout,
                                               int M, int Nn, int Kk, int KCH,
                                               const float* __restrict__ sig, int sigmode) {
  __shared__ __align__(16) unsigned short As[2][128 * 32];
  __shared__ __align__(16) unsigned short Bs[2][128 * 32];
  int t = threadIdx.x;
  int bm0 = blockIdx.x * 128, bn0 = blockIdx.y * 128;
  int wid = t >> 6, lane = t & 63;
  int wm = wid >> 1, wn = wid & 1;

  int kb = 0, ke = Kk;
  if (KCH > 0) { kb = blockIdx.z * KCH; ke = kb + KCH; }

  f32x4 acc[4][4] = {};

  int lrow = t >> 2;
  int lk8 = (((t & 3) ^ ((t >> 3) & 3)) * 8);
  const unsigned short* Ag = A + (size_t)(bm0 + lrow) * Kk + lk8;
  const unsigned short* Bg = Bm + (size_t)(bn0 + lrow) * Kk + lk8;

  int arow = wm * 64 + (lane & 15);
  int brow = wn * 64 + (lane & 15);
  int kca = (((lane >> 4) ^ ((arow >> 1) & 3)) * 8);
  int kcb = (((lane >> 4) ^ ((brow >> 1) & 3)) * 8);

  #define STAGE(nb, koff)                                   \
    do {                                                    \
      gl16(Ag + (koff), &As[nb][wid * 512]);                \
      gl16(Ag + (size_t)64 * Kk + (koff), &As[nb][2048 + wid * 512]); \
      gl16(Bg + (koff), &Bs[nb][wid * 512]);                \
      gl16(Bg + (size_t)64 * Kk + (koff), &Bs[nb][2048 + wid * 512]); \
    } while (0)

  STAGE(0, kb);
  __syncthreads();
  int cb = 0;
  for (int ks = kb; ks < ke; ks += 32) {
    if (ks + 32 < ke) STAGE(cb ^ 1, ks + 32);
    s16x8 af[4], bfr[4];
    #pragma unroll
    for (int i = 0; i < 4; ++i) af[i] = *(const s16x8*)&As[cb][(arow + i * 16) * 32 + kca];
    #pragma unroll
    for (int j = 0; j < 4; ++j) bfr[j] = *(const s16x8*)&Bs[cb][(brow + j * 16) * 32 + kcb];
    #pragma unroll
    for (int i = 0; i < 4; ++i)
      #pragma unroll
      for (int j = 0; j < 4; ++j)
        acc[i][j] = __builtin_amdgcn_mfma_f32_16x16x32_bf16(af[i], bfr[j], acc[i][j], 0, 0, 0);
    __syncthreads();
    cb ^= 1;
  }
  #undef STAGE

  float sc = 1.0f;
  if (sigmode == 1) sc = powf(16.0f * sqrtf(sig[NITER_R] / sig[NITER_R - 1]), -0.125f);

  int crow0 = bm0 + wm * 64 + (lane >> 4) * 4;
  int ccol0 = bn0 + wn * 64 + (lane & 15);
  if constexpr (EPI == 0) {
    unsigned short* C = (unsigned short*)Cout;
    #pragma unroll
    for (int i = 0; i < 4; ++i) {
      #pragma unroll
      for (int j = 0; j < 4; ++j) {
        int col = ccol0 + j * 16;
        float bb = bias[col];
        #pragma unroll
        for (int r = 0; r < 4; ++r) {
          int row = crow0 + i * 16 + r;
          float x = acc[i][j][r] * sc + bb;
          C[(size_t)row * Nn + col] = f2bf(gelu_exact(x));
        }
      }
    }
  } else {
    unsigned short* C = (unsigned short*)Cout + (size_t)blockIdx.z * M * Nn;
    #pragma unroll
    for (int i = 0; i < 4; ++i)
      #pragma unroll
      for (int j = 0; j < 4; ++j) {
        int col = ccol0 + j * 16;
        #pragma unroll
        for (int r = 0; r < 4; ++r) {
          int row = crow0 + i * 16 + r;
          C[(size_t)row * Nn + col] = f2bf(acc[i][j][r]);
        }
      }
  }
}

// sum 8 proj partials, apply sigma^-1 + bias, |h|^2 per row, write bf16 h.
__global__ __launch_bounds__(256) void finish_proj(const unsigned short* __restrict__ Pp,
                                                   const float* __restrict__ bp,
                                                   const float* __restrict__ sc2,
                                                   unsigned short* __restrict__ Hpb,
                                                   float* __restrict__ h2) {
  int wid = threadIdx.x >> 6, lane = threadIdx.x & 63;
  int row = blockIdx.x * 4 + wid;
  float sc = sc2[0];
  float x0 = 0.f, x1 = 0.f;
  #pragma unroll
  for (int z = 0; z < 8; ++z) {
    const unsigned short* pr = Pp + (size_t)z * NB * NKF + (size_t)row * NKF;
    x0 += bf2f(pr[lane]);
    x1 += bf2f(pr[lane + 64]);
  }
  x0 = x0 * sc + bp[lane];
  x1 = x1 * sc + bp[lane + 64];
  float s = x0 * x0 + x1 * x1;
  for (int off = 32; off; off >>= 1) s += __shfl_down(s, off);
  unsigned short* hb = Hpb + (size_t)row * NKF;
  hb[lane] = f2bf(x0);
  hb[lane + 64] = f2bf(x1);
  if (lane == 0) h2[row] = s;
}

// ==================== GP main: MFMA k_xz + logits + var_c ====================
// LDS trim: zs (17.4KB, dead after MFMA phase) unions into kxs (21.5KB) storage.
__global__ __launch_bounds__(256) void gp_main(const unsigned short* __restrict__ Hpb,
                                               const float* __restrict__ h2g,
                                               const unsigned short* __restrict__ zpad,
                                               const float* __restrict__ z2g,
                                               const float* __restrict__ Lig,
                                               const float* __restrict__ alphag,
                                               const float* __restrict__ ll,
                                               float* __restrict__ logitsT,
                                               float* __restrict__ varT) {
  int c = blockIdx.y, b0 = blockIdx.x * 256, t = threadIdx.x;
  int w = t >> 6, lane = t & 63;
  __shared__ __align__(16) float kxs[256][21];   // 21504 B; first 17408 B double as zs
  __shared__ float Ls[NN][21];
  __shared__ float z2s[32], al[NN], ht2[256];
  unsigned short* zs = (unsigned short*)&kxs[0][0];

  {
    const unsigned short* zp = zpad + (size_t)c * 32 * NKF;
    int n = t >> 3, k = (t & 7) * 16;
    u16x8 a = *(const u16x8*)(zp + n * NKF + k);
    u16x8 b = *(const u16x8*)(zp + n * NKF + k + 8);
    *(u16x8*)&zs[n * 136 + k] = a;
    *(u16x8*)&zs[n * 136 + k + 8] = b;
  }
  for (int i = t; i < NN * NN; i += 256) Ls[i / NN][i % NN] = Lig[(size_t)c * NN * NN + i];
  if (t < 32) z2s[t] = (t < NN) ? z2g[c * NN + t] : 0.f;
  if (t < NN) al[t] = alphag[c * NN + t];
  ht2[t] = h2g[b0 + t];
  float inv2 = 0.5f * __expf(-2.0f * ll[0]);
  __syncthreads();

  f32x4 acc[4][2] = {};
  const unsigned short* hbase = Hpb + (size_t)(b0 + w * 64 + (lane & 15)) * NKF + (lane >> 4) * 8;
  #pragma unroll
  for (int ks = 0; ks < 4; ++ks) {
    s16x8 af[4], bfr[2];
    #pragma unroll
    for (int i = 0; i < 4; ++i) af[i] = *(const s16x8*)(hbase + (size_t)i * 16 * NKF + ks * 32);
    #pragma unroll
    for (int j = 0; j < 2; ++j)
      bfr[j] = *(const s16x8*)&zs[(j * 16 + (lane & 15)) * 136 + ks * 32 + (lane >> 4) * 8];
    #pragma unroll
    for (int i = 0; i < 4; ++i)
      #pragma unroll
      for (int j = 0; j < 2; ++j)
        acc[i][j] = __builtin_amdgcn_mfma_f32_16x16x32_bf16(af[i], bfr[j], acc[i][j], 0, 0, 0);
  }
  __syncthreads();  // all zs reads complete before kxs overwrites the same LDS

  #pragma unroll
  for (int i = 0; i < 4; ++i)
    #pragma unroll
    for (int j = 0; j < 2; ++j) {
      int col = j * 16 + (lane & 15);
      #pragma unroll
      for (int r = 0; r < 4; ++r) {
        int rl = w * 64 + i * 16 + (lane >> 4) * 4 + r;
        float d2 = fmaxf(ht2[rl] + z2s[col] - 2.0f * acc[i][j][r], 0.0f);
        float kx = __expf(-d2 * inv2);
        if (col < NN) kxs[rl][col] = kx;
      }
    }
  __syncthreads();

  float kr[NN];
  #pragma unroll
  for (int n = 0; n < NN; ++n) kr[n] = kxs[t][n];
  float lg = 0.f;
  #pragma unroll
  for (int n = 0; n < NN; ++n) lg += kr[n] * al[n];
  logitsT[(size_t)c * NB + b0 + t] = lg;

  float vsum = 0.f;
  #pragma unroll
  for (int n = 0; n < NN; ++n) {
    float wv = 0.f;
    #pragma unroll
    for (int m = 0; m <= n; ++m) wv += Ls[n][m] * kr[m];
    vsum += wv * wv;
  }
  varT[(size_t)c * NB + b0 + t] = fmaxf(1.0f - vsum, 0.0f);
}

// ==================== transpose + softmax + uncertainty mean ====================
__global__ __launch_bounds__(256) void softmax_t(const float* __restrict__ logitsT,
                                                 const float* __restrict__ varT,
                                                 float* __restrict__ probs,
                                                 float* __restrict__ logits_out,
                                                 float* __restrict__ unc) {
  int b0 = blockIdx.x * 64, t = threadIdx.x;
  __shared__ float tile[NC][65];
  __shared__ float redmx[4][64], redsm[4][64], redvs[4][64], mxs[64], invs[64];
  for (int i = t; i < NC * 64; i += 256) {
    int cc = i >> 6, j = i & 63;
    tile[cc][j] = logitsT[(size_t)cc * NB + b0 + j];
  }
  __syncthreads();
  int j = t & 63, p = t >> 6;
  float mx = -1e30f, vs = 0.f;
  for (int cc = p * 50; cc < p * 50 + 50; ++cc) {
    mx = fmaxf(mx, tile[cc][j]);
    vs += varT[(size_t)cc * NB + b0 + j];
  }
  redmx[p][j] = mx;
  redvs[p][j] = vs;
  __syncthreads();
  if (p == 0) {
    mxs[j] = fmaxf(fmaxf(redmx[0][j], redmx[1][j]), fmaxf(redmx[2][j], redmx[3][j]));
    unc[b0 + j] = (redvs[0][j] + redvs[1][j] + redvs[2][j] + redvs[3][j]) * (1.0f / NC);
  }
  __syncthreads();
  float m2 = mxs[j], sm = 0.f;
  for (int cc = p * 50; cc < p * 50 + 50; ++cc) sm += __expf(tile[cc][j] - m2);
  redsm[p][j] = sm;
  __syncthreads();
  if (p == 0) invs[j] = 1.0f / (redsm[0][j] + redsm[1][j] + redsm[2][j] + redsm[3][j]);
  __syncthreads();
  for (int i = t; i < 64 * NC; i += 256) {
    int jj = i / NC, cc = i % NC;
    float lv = tile[cc][jj];
    size_t o = (size_t)(b0 + jj) * NC + cc;
    probs[o] = __expf(lv - mxs[jj]) * invs[jj];
    logits_out[o] = lv;
  }
}

// ==================== launch ====================
extern "C" void kernel_launch(void* const* d_in, const int* in_sizes, int n_in,
                              void* d_out, int out_size, void* d_ws, size_t ws_size,
                              hipStream_t stream) {
  if (ws_size < WS_NEED) return;

  const float* X   = (const float*)d_in[0];
  const float* g1  = (const float*)d_in[1];
  const float* be1 = (const float*)d_in[2];
  const float* W1  = (const float*)d_in[3];
  const float* b1  = (const float*)d_in[4];
  const float* g2  = (const float*)d_in[5];
  const float* be2 = (const float*)d_in[6];
  const float* W2  = (const float*)d_in[7];
  const float* b2  = (const float*)d_in[8];
  const float* Wp  = (const float*)d_in[9];
  const float* bp  = (const float*)d_in[10];
  const float* ll  = (const float*)d_in[11];
  const float* Z   = (const float*)d_in[12];
  const float* VM  = (const float*)d_in[13];

  char* ws = (char*)d_ws;
  unsigned short* W1bf = (unsigned short*)(ws + OFF_W1BF);
  unsigned short* W2bf = (unsigned short*)(ws + OFF_W2BF);
  unsigned short* Wpbf = (unsigned short*)(ws + OFF_WPBF);
  unsigned short* Xbf  = (unsigned short*)(ws + OFF_XBF2);
  unsigned short* H2bf = (unsigned short*)(ws + OFF_H2BF);
  unsigned short* H1bf = (unsigned short*)(ws + OFF_H1BF);
  float* h2s   = (float*)(ws + OFF_H2S);
  float* vb    = (float*)(ws + OFF_PV);
  float* slots = vb + 2 * 2 * 2048;
  float* sinv  = (float*)(ws + OFF_SINV);
  float* z2g   = (float*)(ws + OFF_Z2);
  float* Lg    = (float*)(ws + OFF_LC);
  float* alphag= (float*)(ws + OFF_AL);

  // gram-phase aliases
  unsigned short* W1T  = (unsigned short*)(ws + GOFF_W1T);
  float*          Gpacc= (float*)(ws + GOFF_GPACC);
  unsigned short* G1sA = (unsigned short*)(ws + GOFF_G1SA);
  unsigned short* G1sB = (unsigned short*)(ws + GOFF_G1SB);
  unsigned short* G2sA = (unsigned short*)(ws + GOFF_G2SA);
  unsigned short* G2sB = (unsigned short*)(ws + GOFF_G2SB);
  // GP-phase aliases
  unsigned short* Hpb   = (unsigned short*)(ws + OFF_HPBF);
  unsigned short* Pproj = (unsigned short*)(ws + OFF_PPROJ);
  unsigned short* zpad  = (unsigned short*)(ws + OFF_ZPD);
  float* logitsT = (float*)(ws + OFF_LGT);
  float* varT    = (float*)(ws + OFF_VART);

  float* out    = (float*)d_out;
  float* logits = out + (size_t)NB * NC;
  float* unc    = out + (size_t)2 * NB * NC;

  // ---- prep: bulk memory work (low-VGPR) + standalone GP prep ----
  prep_bulk<<<dim3(1925), 256, 0, stream>>>(X, g1, be1, W1, W2, Wp,
                                            W1T, W1bf, W2bf, Wpbf, Xbf, Gpacc, slots);
  gp_prep<<<dim3(NC), 128, 0, stream>>>(Z, VM, ll, z2g, Lg, alphag, zpad);

  // ---- spectral norms (unsplit gram GEMMs, ping-pong buffers) ----
  gemm_multi<<<dim3(173), 256, 0, stream>>>(W1T, NH, G1sA, W2bf, NH, G2sA,
                                            Wpbf, Gpacc, sinv, 1.0f, 1);
  gemm_multi<<<dim3(158), 256, 0, stream>>>(G1sA, NE, G1sB, G2sA, NH, G2sB,
                                            Wpbf, Gpacc, sinv, 1.0f, 2);
  gemm_multi<<<dim3(157), 256, 0, stream>>>(G1sB, NE, G1sA, G2sB, NH, G2sA,
                                            Wpbf, Gpacc, sinv, 0.0625f, 0);
  for (int i = 0; i < NITER_R; ++i)
    gram_iter<<<dim3(352), 256, 0, stream>>>(G1sA, G2sA, vb, slots, i);

  // ---- MLP (sigma computed inline in epilogues from slots) ----
  gemm_nt<0><<<dim3(NB / 128, NH / 128), 256, 0, stream>>>(Xbf, W1bf, b1, (void*)H1bf, NB, NH, NE, 0, slots, 1);
  ln_h<<<dim3(NB / 4), 256, 0, stream>>>(H1bf, g2, be2, (unsigned short*)(ws + OFF_H1N));
  gemm_nt<0><<<dim3(NB / 128, NH / 128), 256, 0, stream>>>((unsigned short*)(ws + OFF_H1N), W2bf, b2, (void*)H2bf, NB, NH, NH, 0, slots + 16, 1);
  gemm_nt<2><<<dim3(NB / 128, 1, 8), 256, 0, stream>>>(H2bf, Wpbf, nullptr, (void*)Pproj, NB, NKF, NH, NH / 8, nullptr, 0);
  finish_proj<<<dim3(NB / 4), 256, 0, stream>>>(Pproj, bp, sinv + 2, Hpb, h2s);

  // ---- GP head ----
  gp_main<<<dim3(NB / 256, NC), 256, 0, stream>>>(Hpb, h2s, zpad, z2g, Lg, alphag, ll, logitsT, varT);
  softmax_t<<<dim3(NB / 64), 256, 0, stream>>>(logitsT, varT, out, logits, unc);
}

// Round 15
// 396.621 us; speedup vs baseline: 1.0615x; 1.0615x over previous
//
#include <hip/hip_runtime.h>
#include <cstdint>
#include <cstddef>

// ---------------- problem dims ----------------
#define NB 4096   // batch
#define NE 768    // in features
#define NH 2048   // hidden
#define NKF 128   // GP feature dim
#define NC 200    // classes
#define NN 20     // inducing points per class
#define NITER_R 6   // iterations on G^4 (== 24 on G)

typedef __attribute__((ext_vector_type(8))) short s16x8;
typedef __attribute__((ext_vector_type(8))) unsigned short u16x8;
typedef __attribute__((ext_vector_type(4))) unsigned short u16x4;
typedef __attribute__((ext_vector_type(4))) float f32x4;

__device__ inline unsigned short f2bf(float x) {
  unsigned u = __builtin_bit_cast(unsigned, x);
  u += 0x7fffu + ((u >> 16) & 1u);
  return (unsigned short)(u >> 16);
}
__device__ inline float bf2f(unsigned short h) {
  return __builtin_bit_cast(float, (unsigned)h << 16);
}
__device__ inline float gelu_exact(float x) {
  return x * 0.5f * (1.0f + erff(x * 0.70710678118654752f));
}

// async global->LDS 16B/lane. lds base must be wave-uniform; HW writes base+lane*16.
__device__ inline void gl16(const unsigned short* g, unsigned short* l) {
  __builtin_amdgcn_global_load_lds(
      (const __attribute__((address_space(1))) unsigned int*)(uintptr_t)(g),
      (__attribute__((address_space(3))) unsigned int*)(uintptr_t)(l),
      16, 0, 0);
}

// ---------------- workspace layout (bytes) ----------------
constexpr size_t SZ_W1BF = (size_t)NH * NE * 2;
constexpr size_t SZ_W2BF = (size_t)NH * NH * 2;
constexpr size_t SZ_WPBF = (size_t)NKF * NH * 2;
constexpr size_t SZ_SLOT = (size_t)NB * NH * 2;  // 16.8 MB

constexpr size_t OFF_W1BF = 0;                    // persistent unscaled bf16 weights
constexpr size_t OFF_W2BF = OFF_W1BF + SZ_W1BF;
constexpr size_t OFF_WPBF = OFF_W2BF + SZ_W2BF;
constexpr size_t OFF_XBF  = OFF_WPBF + SZ_WPBF;  // slot A
constexpr size_t OFF_H2BF = OFF_XBF;             // gemm2 out (slot A reuse)
constexpr size_t OFF_H1BF = OFF_XBF + SZ_SLOT;   // slot B
constexpr size_t OFF_H1N  = OFF_H1BF + SZ_SLOT;  // slot C
constexpr size_t OFF_HP   = OFF_H1N + SZ_SLOT;   // zpad region (2MB)
constexpr size_t OFF_H2S  = OFF_HP + (size_t)NB * NKF * 4;  // |h|^2 per row
constexpr size_t OFF_PV   = OFF_H2S + (size_t)NB * 4;       // iter vectors + norm slots
constexpr size_t OFF_SINV = OFF_PV + (size_t)3 * 3 * 2048 * 4;
constexpr size_t OFF_Z2   = OFF_SINV + 256;
constexpr size_t OFF_LC   = OFF_Z2 + (size_t)NC * NN * 4;
constexpr size_t OFF_AL   = OFF_LC + (size_t)NC * NN * NN * 4;
constexpr size_t WS_NEED  = OFF_AL + (size_t)NC * NN * 4;

// zpad: bf16 [200][32][128] = 1.64 MB, lives in the OFF_HP region (2 MB)
constexpr size_t OFF_ZPD = OFF_HP;
static_assert((size_t)NC * 32 * NKF * 2 <= (size_t)NB * NKF * 4, "zpad overflow");

// --- slot A sublayout (gram phase + Xbf; all dead before H2bf overwrites) ---
constexpr size_t GOFF_W1T   = OFF_XBF;                            // bf16 [768][2048]
constexpr size_t GOFF_Q0    = GOFF_W1T + (size_t)NE * NH * 2;     // bf16 768^2 partial
constexpr size_t GOFF_Q1    = GOFF_Q0 + (size_t)NE * NE * 2;
constexpr size_t GOFF_GPACC = GOFF_Q1 + (size_t)NE * NE * 2;      // f32 128^2
constexpr size_t GOFF_G1SA  = GOFF_GPACC + (size_t)NKF * NKF * 4; // bf16 768^2 sum
constexpr size_t GOFF_G1SB  = GOFF_G1SA + (size_t)NE * NE * 2;
constexpr size_t OFF_XBF2   = GOFF_G1SB + (size_t)NE * NE * 2;    // bf16 [4096][768] ln1 out
static_assert(OFF_XBF2 + (size_t)NB * NE * 2 <= OFF_XBF + SZ_SLOT, "slotA overflow");
// slot B: G2sA / G2sB bf16 2048^2 each (G2sA doubles as gram_iter's G^4 sum cache)
constexpr size_t GOFF_G2SA = OFF_H1BF;
constexpr size_t GOFF_G2SB = OFF_H1BF + (size_t)NH * NH * 2;
// slot C: P0 / P1 bf16 2048^2 partials (gram); later proj partials + logitsT/varT
constexpr size_t GOFF_P0 = OFF_H1N;
constexpr size_t GOFF_P1 = OFF_H1N + (size_t)NH * NH * 2;
// --- GP-phase aliases ---
constexpr size_t OFF_HPBF  = OFF_H1BF;                         // bf16 [4096][128] (slot B)
constexpr size_t OFF_PPROJ = OFF_H1N;                          // bf16 [8][4096][128] (slot C)
constexpr size_t OFF_LGT   = OFF_H1N;                          // f32 [200][4096] logitsT
constexpr size_t OFF_VART  = OFF_LGT + (size_t)NC * NB * 4;    // f32 [200][4096] var_c
static_assert(OFF_VART + (size_t)NC * NB * 4 <= OFF_H1N + SZ_SLOT, "slotC overflow");

// ==================== prep_bulk: register-homogeneous memory work only ====================
// [0,384): W1 tile -> W1T + W1bf ; [384,896): W2/Wp cast ; [896,1920): ln_e ;
// [1920,1924): zero Gpacc ; [1924]: zero slots
__global__ __launch_bounds__(256) void prep_bulk(const float* __restrict__ X,
                                                 const float* __restrict__ g1,
                                                 const float* __restrict__ be1,
                                                 const float* __restrict__ W1,
                                                 const float* __restrict__ W2,
                                                 const float* __restrict__ Wp,
                                                 unsigned short* __restrict__ W1T,
                                                 unsigned short* __restrict__ W1bf,
                                                 unsigned short* __restrict__ W2bf,
                                                 unsigned short* __restrict__ Wpbf,
                                                 unsigned short* __restrict__ Xbf,
                                                 float* __restrict__ Gpacc,
                                                 float* __restrict__ slots) {
  int b = blockIdx.x, t = threadIdx.x;
  if (b < 384) {
    __shared__ float tile[64][65];
    int bx = b % 12, by = b / 12;
    int c0 = bx * 64, r0 = by * 64;
    int tx = t & 63, ty = t >> 6;
    #pragma unroll
    for (int j = 0; j < 16; ++j) {
      int r = ty + j * 4;
      float v = W1[(size_t)(r0 + r) * NE + c0 + tx];
      tile[r][tx] = v;
      W1bf[(size_t)(r0 + r) * NE + c0 + tx] = f2bf(v);
    }
    __syncthreads();
    #pragma unroll
    for (int j = 0; j < 16; ++j) {
      int cc = ty + j * 4;
      W1T[(size_t)(c0 + cc) * NH + r0 + tx] = f2bf(tile[tx][cc]);
    }
  } else if (b < 896) {
    const int n2v = (NH * NH) / 4;
    const int npv = (NKF * NH) / 4;
    int idx = (b - 384) * 256 + t;
    const int stride = 512 * 256;
    for (int i = idx; i < n2v + npv; i += stride) {
      const float* src; unsigned short* dst; int off;
      if (i < n2v) { src = W2; dst = W2bf; off = i; }
      else         { src = Wp; dst = Wpbf; off = i - n2v; }
      float4 v = *(const float4*)(src + (size_t)off * 4);
      u16x4 o;
      o[0] = f2bf(v.x); o[1] = f2bf(v.y); o[2] = f2bf(v.z); o[3] = f2bf(v.w);
      *(u16x4*)(dst + (size_t)off * 4) = o;
    }
  } else if (b < 1920) {
    int wid = t >> 6, lane = t & 63;
    int row = (b - 896) * 4 + wid;
    const float* xr = X + (size_t)row * NE;
    float4 v[3];
    float s = 0.f, sq = 0.f;
    #pragma unroll
    for (int j = 0; j < 3; ++j) {
      v[j] = *(const float4*)(xr + j * 256 + lane * 4);
      s += v[j].x + v[j].y + v[j].z + v[j].w;
      sq += v[j].x * v[j].x + v[j].y * v[j].y + v[j].z * v[j].z + v[j].w * v[j].w;
    }
    for (int off = 32; off; off >>= 1) { s += __shfl_down(s, off); sq += __shfl_down(sq, off); }
    s = __shfl(s, 0); sq = __shfl(sq, 0);
    float mean = s * (1.0f / NE);
    float var = sq * (1.0f / NE) - mean * mean;
    float rstd = rsqrtf(var + 1e-5f);
    unsigned short* orow = Xbf + (size_t)row * NE;
    #pragma unroll
    for (int j = 0; j < 3; ++j) {
      int e0 = j * 256 + lane * 4;
      float4 gg = *(const float4*)(g1 + e0);
      float4 bb = *(const float4*)(be1 + e0);
      u16x4 o;
      o[0] = f2bf((v[j].x - mean) * rstd * gg.x + bb.x);
      o[1] = f2bf((v[j].y - mean) * rstd * gg.y + bb.y);
      o[2] = f2bf((v[j].z - mean) * rstd * gg.z + bb.z);
      o[3] = f2bf((v[j].w - mean) * rstd * gg.w + bb.w);
      *(u16x4*)(orow + e0) = o;
    }
  } else if (b < 1924) {
    float4 z = {0.f, 0.f, 0.f, 0.f};
    int base = (b - 1920) * 1024 + t;
    #pragma unroll
    for (int q = 0; q < 4; ++q) *((float4*)Gpacc + base + q * 256) = z;
  } else {
    if (t < 32) slots[t] = 0.f;
  }
}

// ==================== gp_prep: z2, Cholesky, alpha, L^-1, zpad (bf16 padded Z) ====================
__global__ __launch_bounds__(128) void gp_prep(const float* __restrict__ z,
                                               const float* __restrict__ vm,
                                               const float* __restrict__ ll,
                                               float* __restrict__ z2g,
                                               float* __restrict__ Lig,
                                               float* __restrict__ alphag,
                                               unsigned short* __restrict__ zpad) {
  int c = blockIdx.x, t = threadIdx.x;
  __shared__ float zc[NN * NKF];
  __shared__ float Amat[NN][NN + 1];
  __shared__ float Li[NN][NN + 1];
  __shared__ float z2s[NN], ys[NN], al[NN];
  const float* zcg = z + (size_t)c * NN * NKF;
  for (int i = t; i < NN * NKF; i += 128) zc[i] = zcg[i];
  __syncthreads();
  if (t < NN) {
    float s = 0.f;
    for (int k = 0; k < NKF; ++k) { float v = zc[t * NKF + k]; s += v * v; }
    z2s[t] = s;
    z2g[c * NN + t] = s;
  }
  __syncthreads();
  float inv2 = 0.5f * expf(-2.0f * ll[0]);
  for (int e = t; e < NN * NN; e += 128) {
    int n = e / NN, m = e % NN;
    float d = 0.f;
    for (int k = 0; k < NKF; ++k) d += zc[n * NKF + k] * zc[m * NKF + k];
    float d2 = fmaxf(z2s[n] + z2s[m] - 2.0f * d, 0.0f);
    float v = expf(-d2 * inv2);
    if (n == m) v += 1e-4f;
    Amat[n][m] = v;
  }
  __syncthreads();
  for (int j = 0; j < NN; ++j) {
    if (t == 0) {
      float s = Amat[j][j];
      for (int p = 0; p < j; ++p) s -= Amat[j][p] * Amat[j][p];
      Amat[j][j] = sqrtf(s);
    }
    __syncthreads();
    if (t > j && t < NN) {
      float s = Amat[t][j];
      for (int p = 0; p < j; ++p) s -= Amat[t][p] * Amat[j][p];
      Amat[t][j] = s / Amat[j][j];
    }
    __syncthreads();
  }
  if (t < NN) {
    int j = t;
    for (int n = 0; n < NN; ++n) {
      float s;
      if (n < j) s = 0.f;
      else {
        s = (n == j) ? 1.f : 0.f;
        for (int m = j; m < n; ++m) s -= Amat[n][m] * Li[m][j];
        s /= Amat[n][n];
      }
      Li[n][j] = s;
    }
  }
  if (t == 0) {
    const float* mc = vm + c * NN;
    for (int n = 0; n < NN; ++n) {
      float s = mc[n];
      for (int m = 0; m < n; ++m) s -= Amat[n][m] * ys[m];
      ys[n] = s / Amat[n][n];
    }
    for (int n = NN - 1; n >= 0; --n) {
      float s = ys[n];
      for (int m = n + 1; m < NN; ++m) s -= Amat[m][n] * al[m];
      al[n] = s / Amat[n][n];
    }
  }
  __syncthreads();
  for (int e = t; e < NN * NN; e += 128)
    Lig[(size_t)c * NN * NN + e] = Li[e / NN][e % NN];
  if (t < NN) alphag[c * NN + t] = al[t];
  unsigned short* zp = zpad + (size_t)c * 32 * NKF;
  for (int i = t; i < 32 * NKF; i += 128) {
    int n = i >> 7;
    zp[i] = (n < NN) ? f2bf(zc[n * NKF + (i & 127)]) : (unsigned short)0;
  }
}

// ==================== symmetric dual-job gram GEMM + folded Gp jobs ====================
// [0,42): G1 (21 tri tiles x 2 kz); [42,314): G2 (136 x 2).
// extra==1: blocks [314,330) = Gp = Wp*Wp^T split-K16, fp32 atomics into Gpacc.
// extra==2: block 314 = gp_power on Gpacc -> sinv[2] (reuses As/Bs LDS).
__global__ __launch_bounds__(256) void gemm_multi(const unsigned short* __restrict__ A1, int K1,
                                                  unsigned short* __restrict__ O1a,
                                                  unsigned short* __restrict__ O1b,
                                                  const unsigned short* __restrict__ A2, int K2,
                                                  unsigned short* __restrict__ O2a,
                                                  unsigned short* __restrict__ O2b,
                                                  const unsigned short* __restrict__ Wpb,
                                                  float* __restrict__ Gpacc,
                                                  float* __restrict__ sinv,
                                                  float cscale, int extra) {
  __shared__ __align__(16) unsigned short As[2][128 * 32];
  __shared__ __align__(16) unsigned short Bs[2][128 * 32];
  __shared__ __align__(16) unsigned short Tb[64][136];
  int b = blockIdx.x, t = threadIdx.x;

  if (extra == 2 && b == 314) {
    float* vv = (float*)&As[0][0];
    float* nacc = vv + 160;
    float (*pred)[NKF] = (float(*)[NKF]) & Bs[0][0];
    int rg = (t & 31) * 4;
    int ks2 = t >> 5;
    f32x4 Greg[16];
    #pragma unroll
    for (int kk = 0; kk < 16; ++kk)
      Greg[kk] = *(const f32x4*)(Gpacc + (size_t)(ks2 * 16 + kk) * NKF + rg);
    if (t < NKF) vv[t] = 1.0f;
    __syncthreads();
    float s_last0 = 1.f, s_last1 = 1.f;
    for (int it = 0; it < 40; ++it) {
      f32x4 p = {0.f, 0.f, 0.f, 0.f};
      #pragma unroll
      for (int kq = 0; kq < 4; ++kq) {
        f32x4 vq = *(const f32x4*)&vv[ks2 * 16 + kq * 4];
        p += Greg[kq * 4 + 0] * vq[0];
        p += Greg[kq * 4 + 1] * vq[1];
        p += Greg[kq * 4 + 2] * vq[2];
        p += Greg[kq * 4 + 3] * vq[3];
      }
      *(f32x4*)&pred[ks2][rg] = p;
      __syncthreads();
      float s = 0.f;
      if (t < NKF) {
        #pragma unroll
        for (int q = 0; q < 8; ++q) s += pred[q][t];
        vv[t] = s;
      }
      if (it >= 38) {
        float q2 = (t < NKF) ? s * s : 0.f;
        #pragma unroll
        for (int off = 32; off; off >>= 1) q2 += __shfl_down(q2, off);
        if (t == 0) nacc[0] = q2;
        if (t == 64) nacc[1] = q2;
      }
      __syncthreads();
      if (it == 38 && t == 0) s_last0 = nacc[0] + nacc[1];
      if (it == 39 && t == 0) s_last1 = nacc[0] + nacc[1];
    }
    if (t == 0) sinv[2] = powf(s_last1 / s_last0, -0.25f);
    return;
  }

  int epimode = 0;
  const unsigned short* A;
  unsigned short* Cout = nullptr;
  int Kk, Nn, kb, ke, bm0, bn0;
  if (extra == 1 && b >= 314) {
    int idx = b - 314;
    A = Wpb; Kk = K2; Nn = NKF;
    kb = idx * 128; ke = kb + 128;
    bm0 = 0; bn0 = 0;
    epimode = 1;
  } else {
    int ti;
    if (b < 42) {
      int kz = b / 21; ti = b % 21;
      A = A1; Kk = K1; Nn = NE;
      Cout = kz ? O1b : O1a;
      kb = kz * (K1 / 2); ke = kb + K1 / 2;
    } else {
      int idx = b - 42;
      int kz = idx / 136; ti = idx % 136;
      A = A2; Kk = K2; Nn = NH;
      Cout = kz ? O2b : O2a;
      kb = kz * (K2 / 2); ke = kb + K2 / 2;
    }
    int ri = 0;
    while ((ri + 1) * (ri + 2) / 2 <= ti) ++ri;
    int rj = ti - ri * (ri + 1) / 2;
    bm0 = ri * 128; bn0 = rj * 128;
  }

  int wid = t >> 6, lane = t & 63;
  int wm = wid >> 1, wn = wid & 1;
  f32x4 acc[4][4] = {};

  int lrow = t >> 2;
  int lk8 = (((t & 3) ^ ((t >> 3) & 3)) * 8);
  const unsigned short* Ag = A + (size_t)(bm0 + lrow) * Kk + lk8;
  const unsigned short* Bg = A + (size_t)(bn0 + lrow) * Kk + lk8;

  int arow = wm * 64 + (lane & 15);
  int brow = wn * 64 + (lane & 15);
  int kca = (((lane >> 4) ^ ((arow >> 1) & 3)) * 8);
  int kcb = (((lane >> 4) ^ ((brow >> 1) & 3)) * 8);

  #define STAGEM(nb, koff)                                  \
    do {                                                    \
      gl16(Ag + (koff), &As[nb][wid * 512]);                \
      gl16(Ag + (size_t)64 * Kk + (koff), &As[nb][2048 + wid * 512]); \
      gl16(Bg + (koff), &Bs[nb][wid * 512]);                \
      gl16(Bg + (size_t)64 * Kk + (koff), &Bs[nb][2048 + wid * 512]); \
    } while (0)

  STAGEM(0, kb);
  __syncthreads();
  int cb = 0;
  for (int ks = kb; ks < ke; ks += 32) {
    if (ks + 32 < ke) STAGEM(cb ^ 1, ks + 32);
    s16x8 af[4], bfr[4];
    #pragma unroll
    for (int i = 0; i < 4; ++i) af[i] = *(const s16x8*)&As[cb][(arow + i * 16) * 32 + kca];
    #pragma unroll
    for (int j = 0; j < 4; ++j) bfr[j] = *(const s16x8*)&Bs[cb][(brow + j * 16) * 32 + kcb];
    #pragma unroll
    for (int i = 0; i < 4; ++i)
      #pragma unroll
      for (int j = 0; j < 4; ++j)
        acc[i][j] = __builtin_amdgcn_mfma_f32_16x16x32_bf16(af[i], bfr[j], acc[i][j], 0, 0, 0);
    __syncthreads();
    cb ^= 1;
  }
  #undef STAGEM

  int crow0 = bm0 + wm * 64 + (lane >> 4) * 4;
  int ccol0 = bn0 + wn * 64 + (lane & 15);
  if (epimode == 1) {
    #pragma unroll
    for (int i = 0; i < 4; ++i)
      #pragma unroll
      for (int j = 0; j < 4; ++j) {
        int col = ccol0 + j * 16;
        #pragma unroll
        for (int r = 0; r < 4; ++r) {
          int row = crow0 + i * 16 + r;
          atomicAdd(&Gpacc[(size_t)row * NKF + col], acc[i][j][r]);
        }
      }
    return;
  }

  #pragma unroll
  for (int i = 0; i < 4; ++i)
    #pragma unroll
    for (int j = 0; j < 4; ++j) {
      int col = ccol0 + j * 16;
      #pragma unroll
      for (int r = 0; r < 4; ++r) {
        int row = crow0 + i * 16 + r;
        Cout[(size_t)row * Nn + col] = f2bf(acc[i][j][r] * cscale);
      }
    }

  if (bm0 != bn0) {
    #pragma unroll
    for (int h = 0; h < 2; ++h) {
      __syncthreads();
      if (wn == h) {
        #pragma unroll
        for (int i = 0; i < 4; ++i)
          #pragma unroll
          for (int j = 0; j < 4; ++j) {
            int lc = j * 16 + (lane & 15);
            #pragma unroll
            for (int r = 0; r < 4; ++r) {
              int lr = wm * 64 + i * 16 + (lane >> 4) * 4 + r;
              Tb[lc][lr] = f2bf(acc[i][j][r] * cscale);
            }
          }
      }
      __syncthreads();
      int c = t >> 2;
      int rs = (t & 3) * 32;
      unsigned short* dst = Cout + (size_t)(bn0 + h * 64 + c) * Nn + bm0 + rs;
      #pragma unroll
      for (int q = 0; q < 4; ++q) *(u16x8*)(dst + q * 8) = *(const u16x8*)&Tb[c][rs + q * 8];
    }
  }
}

// routed partial-add: G1o = Q0+Q1 (768^2), G2o = P0+P1 (2048^2), bf16
__global__ __launch_bounds__(256) void add2(const unsigned short* __restrict__ Q0,
                                            const unsigned short* __restrict__ Q1,
                                            unsigned short* __restrict__ G1o,
                                            const unsigned short* __restrict__ P0,
                                            const unsigned short* __restrict__ P1,
                                            unsigned short* __restrict__ G2o) {
  const int n1 = (NE * NE) / 8;
  const int n2 = (NH * NH) / 8;
  int idx = blockIdx.x * 256 + threadIdx.x;
  for (int i = idx; i < n1 + n2; i += gridDim.x * 256) {
    const unsigned short *a, *bb; unsigned short* o; int off;
    if (i < n1) { a = Q0; bb = Q1; o = G1o; off = i; }
    else        { a = P0; bb = P1; o = G2o; off = i - n1; }
    u16x8 x = *(const u16x8*)(a + (size_t)off * 8);
    u16x8 y = *(const u16x8*)(bb + (size_t)off * 8);
    u16x8 r;
    #pragma unroll
    for (int q = 0; q < 8; ++q) r[q] = f2bf(bf2f(x[q]) + bf2f(y[q]));
    *(u16x8*)(o + (size_t)off * 8) = r;
  }
}

// ==================== gram power iteration ====================
// iter 0: reads split-K partials (v = ones), caches summed G^4 into G1s/G2s.
// iters >=1: read the cached sum (half the traffic).
__global__ __launch_bounds__(256) void gram_iter(const unsigned short* __restrict__ Q0,
                                                 const unsigned short* __restrict__ Q1,
                                                 const unsigned short* __restrict__ P0,
                                                 const unsigned short* __restrict__ P1,
                                                 unsigned short* __restrict__ G1s,
                                                 unsigned short* __restrict__ G2s,
                                                 float* __restrict__ vb,
                                                 float* __restrict__ slots, int iter) {
  int b = blockIdx.x, t = threadIdx.x;
  int m, r0, Kd;
  const unsigned short *ga, *gb;
  unsigned short* gs;
  if (b < 96) { m = 0; ga = Q0; gb = Q1; gs = G1s; Kd = NE; r0 = b * 8; }
  else        { m = 1; ga = P0; gb = P1; gs = G2s; Kd = NH; r0 = (b - 96) * 8; }

  const float* vin = vb + ((size_t)m * 2 + (iter & 1)) * 2048;
  float* vout      = vb + ((size_t)m * 2 + ((iter + 1) & 1)) * 2048;

  __shared__ float vs[2048];
  if (iter > 0) {
    for (int k = t; k < Kd; k += 256) vs[k] = vin[k];
    __syncthreads();
  }

  int w = t >> 6, lane = t & 63;
  float nrm = 0.f;
  #pragma unroll
  for (int rr = 0; rr < 2; ++rr) {
    int row = r0 + w * 2 + rr;
    float s = 0.f;
    if (iter == 0) {
      const unsigned short* g0 = ga + (size_t)row * Kd;
      const unsigned short* g1 = gb + (size_t)row * Kd;
      unsigned short* gw = gs + (size_t)row * Kd;
      for (int k0 = lane * 8; k0 < Kd; k0 += 512) {
        u16x8 u = *(const u16x8*)(g0 + k0);
        u16x8 u2 = *(const u16x8*)(g1 + k0);
        u16x8 o;
        #pragma unroll
        for (int q = 0; q < 8; ++q) {
          float gval = bf2f(u[q]) + bf2f(u2[q]);
          o[q] = f2bf(gval);
          s += gval;  // v = ones
        }
        *(u16x8*)(gw + k0) = o;
      }
    } else {
      const unsigned short* g0 = gs + (size_t)row * Kd;
      for (int k0 = lane * 8; k0 < Kd; k0 += 512) {
        u16x8 u = *(const u16x8*)(g0 + k0);
        #pragma unroll
        for (int q = 0; q < 8; ++q) s += bf2f(u[q]) * vs[k0 + q];
      }
    }
    for (int off = 32; off; off >>= 1) s += __shfl_down(s, off);
    if (lane == 0) { vout[row] = s; nrm += s * s; }
  }
  if (lane == 0) atomicAdd(&slots[m * 16 + iter + 1], nrm);
}

// ==================== ln_h ====================
__global__ __launch_bounds__(256) void ln_h(const unsigned short* __restrict__ X,
                                            const float* __restrict__ g,
                                            const float* __restrict__ b,
                                            unsigned short* __restrict__ out) {
  int wid = threadIdx.x >> 6, lane = threadIdx.x & 63;
  int row = blockIdx.x * 4 + wid;
  const unsigned short* xr = X + (size_t)row * NH;
  float xv[32];
  float s = 0.f, sq = 0.f;
  #pragma unroll
  for (int j = 0; j < 4; ++j) {
    u16x8 u = *(const u16x8*)(xr + j * 512 + lane * 8);
    #pragma unroll
    for (int q = 0; q < 8; ++q) {
      float x = bf2f(u[q]);
      xv[j * 8 + q] = x; s += x; sq += x * x;
    }
  }
  for (int off = 32; off; off >>= 1) { s += __shfl_down(s, off); sq += __shfl_down(sq, off); }
  s = __shfl(s, 0); sq = __shfl(sq, 0);
  float mean = s * (1.0f / NH);
  float var = sq * (1.0f / NH) - mean * mean;
  float rstd = rsqrtf(var + 1e-5f);
  unsigned short* orow = out + (size_t)row * NH;
  #pragma unroll
  for (int j = 0; j < 4; ++j) {
    int e0 = j * 512 + lane * 8;
    float4 ga = *(const float4*)(g + e0);
    float4 gb = *(const float4*)(g + e0 + 4);
    float4 ba = *(const float4*)(b + e0);
    float4 bb = *(const float4*)(b + e0 + 4);
    u16x8 o;
    o[0] = f2bf((xv[j*8+0] - mean) * rstd * ga.x + ba.x);
    o[1] = f2bf((xv[j*8+1] - mean) * rstd * ga.y + ba.y);
    o[2] = f2bf((xv[j*8+2] - mean) * rstd * ga.z + ba.z);
    o[3] = f2bf((xv[j*8+3] - mean) * rstd * ga.w + ba.w);
    o[4] = f2bf((xv[j*8+4] - mean) * rstd * gb.x + bb.x);
    o[5] = f2bf((xv[j*8+5] - mean) * rstd * gb.y + bb.y);
    o[6] = f2bf((xv[j*8+6] - mean) * rstd * gb.z + bb.z);
    o[7] = f2bf((xv[j*8+7] - mean) * rstd * gb.w + bb.w);
    *(u16x8*)(orow + e0) = o;
  }
}

// ==================== bf16 MFMA GEMM (NT), 2-phase dbuf + T2 XOR swizzle ====================
// sigmode 1: sc = sigma^-1 derived inline from power-iter slots.
// EPI 0: gelu(acc*sc+bias)->bf16. EPI 2: raw bf16 partials per blockIdx.z (split-K).
template <int EPI>
__global__ __launch_bounds__(256) void gemm_nt(const unsigned short* __restrict__ A,
                                               const unsigned short* __restrict__ Bm,
                                               const float* __restrict__ bias,
                                               void* __restrict__ Cout,
                                               int M, int Nn, int Kk, int KCH,
                                               const float* __restrict__ sig, int sigmode) {
  __shared__ __align__(16) unsigned short As[2][128 * 32];
  __shared__ __align__(16) unsigned short Bs[2][128 * 32];
  int t = threadIdx.x;
  int bm0 = blockIdx.x * 128, bn0 = blockIdx.y * 128;
  int wid = t >> 6, lane = t & 63;
  int wm = wid >> 1, wn = wid & 1;

  int kb = 0, ke = Kk;
  if (KCH > 0) { kb = blockIdx.z * KCH; ke = kb + KCH; }

  f32x4 acc[4][4] = {};

  int lrow = t >> 2;
  int lk8 = (((t & 3) ^ ((t >> 3) & 3)) * 8);
  const unsigned short* Ag = A + (size_t)(bm0 + lrow) * Kk + lk8;
  const unsigned short* Bg = Bm + (size_t)(bn0 + lrow) * Kk + lk8;

  int arow = wm * 64 + (lane & 15);
  int brow = wn * 64 + (lane & 15);
  int kca = (((lane >> 4) ^ ((arow >> 1) & 3)) * 8);
  int kcb = (((lane >> 4) ^ ((brow >> 1) & 3)) * 8);

  #define STAGE(nb, koff)                                   \
    do {                                                    \
      gl16(Ag + (koff), &As[nb][wid * 512]);                \
      gl16(Ag + (size_t)64 * Kk + (koff), &As[nb][2048 + wid * 512]); \
      gl16(Bg + (koff), &Bs[nb][wid * 512]);                \
      gl16(Bg + (size_t)64 * Kk + (koff), &Bs[nb][2048 + wid * 512]); \
    } while (0)

  STAGE(0, kb);
  __syncthreads();
  int cb = 0;
  for (int ks = kb; ks < ke; ks += 32) {
    if (ks + 32 < ke) STAGE(cb ^ 1, ks + 32);
    s16x8 af[4], bfr[4];
    #pragma unroll
    for (int i = 0; i < 4; ++i) af[i] = *(const s16x8*)&As[cb][(arow + i * 16) * 32 + kca];
    #pragma unroll
    for (int j = 0; j < 4; ++j) bfr[j] = *(const s16x8*)&Bs[cb][(brow + j * 16) * 32 + kcb];
    #pragma unroll
    for (int i = 0; i < 4; ++i)
      #pragma unroll
      for (int j = 0; j < 4; ++j)
        acc[i][j] = __builtin_amdgcn_mfma_f32_16x16x32_bf16(af[i], bfr[j], acc[i][j], 0, 0, 0);
    __syncthreads();
    cb ^= 1;
  }
  #undef STAGE

  float sc = 1.0f;
  if (sigmode == 1) sc = powf(16.0f * sqrtf(sig[NITER_R] / sig[NITER_R - 1]), -0.125f);

  int crow0 = bm0 + wm * 64 + (lane >> 4) * 4;
  int ccol0 = bn0 + wn * 64 + (lane & 15);
  if constexpr (EPI == 0) {
    unsigned short* C = (unsigned short*)Cout;
    #pragma unroll
    for (int i = 0; i < 4; ++i) {
      #pragma unroll
      for (int j = 0; j < 4; ++j) {
        int col = ccol0 + j * 16;
        float bb = bias[col];
        #pragma unroll
        for (int r = 0; r < 4; ++r) {
          int row = crow0 + i * 16 + r;
          float x = acc[i][j][r] * sc + bb;
          C[(size_t)row * Nn + col] = f2bf(gelu_exact(x));
        }
      }
    }
  } else {
    unsigned short* C = (unsigned short*)Cout + (size_t)blockIdx.z * M * Nn;
    #pragma unroll
    for (int i = 0; i < 4; ++i)
      #pragma unroll
      for (int j = 0; j < 4; ++j) {
        int col = ccol0 + j * 16;
        #pragma unroll
        for (int r = 0; r < 4; ++r) {
          int row = crow0 + i * 16 + r;
          C[(size_t)row * Nn + col] = f2bf(acc[i][j][r]);
        }
      }
  }
}

// sum 8 proj partials, apply sigma^-1 + bias, |h|^2 per row, write bf16 h.
__global__ __launch_bounds__(256) void finish_proj(const unsigned short* __restrict__ Pp,
                                                   const float* __restrict__ bp,
                                                   const float* __restrict__ sc2,
                                                   unsigned short* __restrict__ Hpb,
                                                   float* __restrict__ h2) {
  int wid = threadIdx.x >> 6, lane = threadIdx.x & 63;
  int row = blockIdx.x * 4 + wid;
  float sc = sc2[0];
  float x0 = 0.f, x1 = 0.f;
  #pragma unroll
  for (int z = 0; z < 8; ++z) {
    const unsigned short* pr = Pp + (size_t)z * NB * NKF + (size_t)row * NKF;
    x0 += bf2f(pr[lane]);
    x1 += bf2f(pr[lane + 64]);
  }
  x0 = x0 * sc + bp[lane];
  x1 = x1 * sc + bp[lane + 64];
  float s = x0 * x0 + x1 * x1;
  for (int off = 32; off; off >>= 1) s += __shfl_down(s, off);
  unsigned short* hb = Hpb + (size_t)row * NKF;
  hb[lane] = f2bf(x0);
  hb[lane + 64] = f2bf(x1);
  if (lane == 0) h2[row] = s;
}

// ==================== GP main: MFMA k_xz + logits + var_c ====================
// LDS trim: zs (17.4KB, dead after MFMA phase) unions into kxs (21.5KB) storage.
__global__ __launch_bounds__(256) void gp_main(const unsigned short* __restrict__ Hpb,
                                               const float* __restrict__ h2g,
                                               const unsigned short* __restrict__ zpad,
                                               const float* __restrict__ z2g,
                                               const float* __restrict__ Lig,
                                               const float* __restrict__ alphag,
                                               const float* __restrict__ ll,
                                               float* __restrict__ logitsT,
                                               float* __restrict__ varT) {
  int c = blockIdx.y, b0 = blockIdx.x * 256, t = threadIdx.x;
  int w = t >> 6, lane = t & 63;
  __shared__ __align__(16) float kxs[256][21];   // 21504 B; first 17408 B double as zs
  __shared__ float Ls[NN][21];
  __shared__ float z2s[32], al[NN], ht2[256];
  unsigned short* zs = (unsigned short*)&kxs[0][0];

  {
    const unsigned short* zp = zpad + (size_t)c * 32 * NKF;
    int n = t >> 3, k = (t & 7) * 16;
    u16x8 a = *(const u16x8*)(zp + n * NKF + k);
    u16x8 b = *(const u16x8*)(zp + n * NKF + k + 8);
    *(u16x8*)&zs[n * 136 + k] = a;
    *(u16x8*)&zs[n * 136 + k + 8] = b;
  }
  for (int i = t; i < NN * NN; i += 256) Ls[i / NN][i % NN] = Lig[(size_t)c * NN * NN + i];
  if (t < 32) z2s[t] = (t < NN) ? z2g[c * NN + t] : 0.f;
  if (t < NN) al[t] = alphag[c * NN + t];
  ht2[t] = h2g[b0 + t];
  float inv2 = 0.5f * __expf(-2.0f * ll[0]);
  __syncthreads();

  f32x4 acc[4][2] = {};
  const unsigned short* hbase = Hpb + (size_t)(b0 + w * 64 + (lane & 15)) * NKF + (lane >> 4) * 8;
  #pragma unroll
  for (int ks = 0; ks < 4; ++ks) {
    s16x8 af[4], bfr[2];
    #pragma unroll
    for (int i = 0; i < 4; ++i) af[i] = *(const s16x8*)(hbase + (size_t)i * 16 * NKF + ks * 32);
    #pragma unroll
    for (int j = 0; j < 2; ++j)
      bfr[j] = *(const s16x8*)&zs[(j * 16 + (lane & 15)) * 136 + ks * 32 + (lane >> 4) * 8];
    #pragma unroll
    for (int i = 0; i < 4; ++i)
      #pragma unroll
      for (int j = 0; j < 2; ++j)
        acc[i][j] = __builtin_amdgcn_mfma_f32_16x16x32_bf16(af[i], bfr[j], acc[i][j], 0, 0, 0);
  }
  __syncthreads();  // all zs reads complete before kxs overwrites the same LDS

  #pragma unroll
  for (int i = 0; i < 4; ++i)
    #pragma unroll
    for (int j = 0; j < 2; ++j) {
      int col = j * 16 + (lane & 15);
      #pragma unroll
      for (int r = 0; r < 4; ++r) {
        int rl = w * 64 + i * 16 + (lane >> 4) * 4 + r;
        float d2 = fmaxf(ht2[rl] + z2s[col] - 2.0f * acc[i][j][r], 0.0f);
        float kx = __expf(-d2 * inv2);
        if (col < NN) kxs[rl][col] = kx;
      }
    }
  __syncthreads();

  float kr[NN];
  #pragma unroll
  for (int n = 0; n < NN; ++n) kr[n] = kxs[t][n];
  float lg = 0.f;
  #pragma unroll
  for (int n = 0; n < NN; ++n) lg += kr[n] * al[n];
  logitsT[(size_t)c * NB + b0 + t] = lg;

  float vsum = 0.f;
  #pragma unroll
  for (int n = 0; n < NN; ++n) {
    float wv = 0.f;
    #pragma unroll
    for (int m = 0; m <= n; ++m) wv += Ls[n][m] * kr[m];
    vsum += wv * wv;
  }
  varT[(size_t)c * NB + b0 + t] = fmaxf(1.0f - vsum, 0.0f);
}

// ==================== transpose + softmax + uncertainty mean ====================
__global__ __launch_bounds__(256) void softmax_t(const float* __restrict__ logitsT,
                                                 const float* __restrict__ varT,
                                                 float* __restrict__ probs,
                                                 float* __restrict__ logits_out,
                                                 float* __restrict__ unc) {
  int b0 = blockIdx.x * 64, t = threadIdx.x;
  __shared__ float tile[NC][65];
  __shared__ float redmx[4][64], redsm[4][64], redvs[4][64], mxs[64], invs[64];
  for (int i = t; i < NC * 64; i += 256) {
    int cc = i >> 6, j = i & 63;
    tile[cc][j] = logitsT[(size_t)cc * NB + b0 + j];
  }
  __syncthreads();
  int j = t & 63, p = t >> 6;
  float mx = -1e30f, vs = 0.f;
  for (int cc = p * 50; cc < p * 50 + 50; ++cc) {
    mx = fmaxf(mx, tile[cc][j]);
    vs += varT[(size_t)cc * NB + b0 + j];
  }
  redmx[p][j] = mx;
  redvs[p][j] = vs;
  __syncthreads();
  if (p == 0) {
    mxs[j] = fmaxf(fmaxf(redmx[0][j], redmx[1][j]), fmaxf(redmx[2][j], redmx[3][j]));
    unc[b0 + j] = (redvs[0][j] + redvs[1][j] + redvs[2][j] + redvs[3][j]) * (1.0f / NC);
  }
  __syncthreads();
  float m2 = mxs[j], sm = 0.f;
  for (int cc = p * 50; cc < p * 50 + 50; ++cc) sm += __expf(tile[cc][j] - m2);
  redsm[p][j] = sm;
  __syncthreads();
  if (p == 0) invs[j] = 1.0f / (redsm[0][j] + redsm[1][j] + redsm[2][j] + redsm[3][j]);
  __syncthreads();
  for (int i = t; i < 64 * NC; i += 256) {
    int jj = i / NC, cc = i % NC;
    float lv = tile[cc][jj];
    size_t o = (size_t)(b0 + jj) * NC + cc;
    probs[o] = __expf(lv - mxs[jj]) * invs[jj];
    logits_out[o] = lv;
  }
}

// ==================== launch ====================
extern "C" void kernel_launch(void* const* d_in, const int* in_sizes, int n_in,
                              void* d_out, int out_size, void* d_ws, size_t ws_size,
                              hipStream_t stream) {
  if (ws_size < WS_NEED) return;

  const float* X   = (const float*)d_in[0];
  const float* g1  = (const float*)d_in[1];
  const float* be1 = (const float*)d_in[2];
  const float* W1  = (const float*)d_in[3];
  const float* b1  = (const float*)d_in[4];
  const float* g2  = (const float*)d_in[5];
  const float* be2 = (const float*)d_in[6];
  const float* W2  = (const float*)d_in[7];
  const float* b2  = (const float*)d_in[8];
  const float* Wp  = (const float*)d_in[9];
  const float* bp  = (const float*)d_in[10];
  const float* ll  = (const float*)d_in[11];
  const float* Z   = (const float*)d_in[12];
  const float* VM  = (const float*)d_in[13];

  char* ws = (char*)d_ws;
  unsigned short* W1bf = (unsigned short*)(ws + OFF_W1BF);
  unsigned short* W2bf = (unsigned short*)(ws + OFF_W2BF);
  unsigned short* Wpbf = (unsigned short*)(ws + OFF_WPBF);
  unsigned short* Xbf  = (unsigned short*)(ws + OFF_XBF2);
  unsigned short* H2bf = (unsigned short*)(ws + OFF_H2BF);
  unsigned short* H1bf = (unsigned short*)(ws + OFF_H1BF);
  unsigned short* H1n  = (unsigned short*)(ws + OFF_H1N);
  float* h2s   = (float*)(ws + OFF_H2S);
  float* vb    = (float*)(ws + OFF_PV);
  float* slots = vb + 2 * 2 * 2048;
  float* sinv  = (float*)(ws + OFF_SINV);
  float* z2g   = (float*)(ws + OFF_Z2);
  float* Lg    = (float*)(ws + OFF_LC);
  float* alphag= (float*)(ws + OFF_AL);

  // gram-phase aliases
  unsigned short* W1T  = (unsigned short*)(ws + GOFF_W1T);
  unsigned short* Q0   = (unsigned short*)(ws + GOFF_Q0);
  unsigned short* Q1   = (unsigned short*)(ws + GOFF_Q1);
  float*          Gpacc= (float*)(ws + GOFF_GPACC);
  unsigned short* G1sA = (unsigned short*)(ws + GOFF_G1SA);
  unsigned short* G1sB = (unsigned short*)(ws + GOFF_G1SB);
  unsigned short* G2sA = (unsigned short*)(ws + GOFF_G2SA);
  unsigned short* G2sB = (unsigned short*)(ws + GOFF_G2SB);
  unsigned short* P0   = (unsigned short*)(ws + GOFF_P0);
  unsigned short* P1   = (unsigned short*)(ws + GOFF_P1);
  // GP-phase aliases
  unsigned short* Hpb   = (unsigned short*)(ws + OFF_HPBF);
  unsigned short* Pproj = (unsigned short*)(ws + OFF_PPROJ);
  unsigned short* zpad  = (unsigned short*)(ws + OFF_ZPD);
  float* logitsT = (float*)(ws + OFF_LGT);
  float* varT    = (float*)(ws + OFF_VART);

  float* out    = (float*)d_out;
  float* logits = out + (size_t)NB * NC;
  float* unc    = out + (size_t)2 * NB * NC;

  // ---- prep: bulk memory work (low-VGPR) + standalone GP prep ----
  prep_bulk<<<dim3(1925), 256, 0, stream>>>(X, g1, be1, W1, W2, Wp,
                                            W1T, W1bf, W2bf, Wpbf, Xbf, Gpacc, slots);
  gp_prep<<<dim3(NC), 128, 0, stream>>>(Z, VM, ll, z2g, Lg, alphag, zpad);

  // ---- spectral norms ----
  gemm_multi<<<dim3(330), 256, 0, stream>>>(W1T, NH, Q0, Q1, W2bf, NH, P0, P1,
                                            Wpbf, Gpacc, sinv, 1.0f, 1);
  add2<<<dim3(1024), 256, 0, stream>>>(Q0, Q1, G1sA, P0, P1, G2sA);
  gemm_multi<<<dim3(315), 256, 0, stream>>>(G1sA, NE, Q0, Q1, G2sA, NH, P0, P1,
                                            Wpbf, Gpacc, sinv, 1.0f, 2);
  add2<<<dim3(1024), 256, 0, stream>>>(Q0, Q1, G1sB, P0, P1, G2sB);
  gemm_multi<<<dim3(314), 256, 0, stream>>>(G1sB, NE, Q0, Q1, G2sB, NH, P0, P1,
                                            Wpbf, Gpacc, sinv, 0.0625f, 0);
  for (int i = 0; i < NITER_R; ++i)
    gram_iter<<<dim3(352), 256, 0, stream>>>(Q0, Q1, P0, P1, G1sA, G2sA, vb, slots, i);

  // ---- MLP (sigma computed inline in epilogues from slots) ----
  gemm_nt<0><<<dim3(NB / 128, NH / 128), 256, 0, stream>>>(Xbf, W1bf, b1, (void*)H1bf, NB, NH, NE, 0, slots, 1);
  ln_h<<<dim3(NB / 4), 256, 0, stream>>>(H1bf, g2, be2, H1n);
  gemm_nt<0><<<dim3(NB / 128, NH / 128), 256, 0, stream>>>(H1n, W2bf, b2, (void*)H2bf, NB, NH, NH, 0, slots + 16, 1);
  gemm_nt<2><<<dim3(NB / 128, 1, 8), 256, 0, stream>>>(H2bf, Wpbf, nullptr, (void*)Pproj, NB, NKF, NH, NH / 8, nullptr, 0);
  finish_proj<<<dim3(NB / 4), 256, 0, stream>>>(Pproj, bp, sinv + 2, Hpb, h2s);

  // ---- GP head ----
  gp_main<<<dim3(NB / 256, NC), 256, 0, stream>>>(Hpb, h2s, zpad, z2g, Lg, alphag, ll, logitsT, varT);
  softmax_t<<<dim3(NB / 64), 256, 0, stream>>>(logitsT, varT, out, logits, unc);
}